// Round 10
// baseline (168.730 us; speedup 1.0000x reference)
//
#include <hip/hip_runtime.h>
#include <hip/hip_cooperative_groups.h>
#include <stdint.h>

namespace cg = cooperative_groups;

// Problem: B=32, P=16, E=50000, H=128
#define E_DIM 50000
#define EP2   50176          // padded: 112 * 448 = 784 * 64
#define HD    128
#define BD    32
#define PD    16
#define MD    512            // B*P
#define NKC   112            // k-chunks of 448
#define NST   7              // 64-e stages per chunk
#define NEB   784            // embF 64-e units = EP2/64
#define GRID  256
#define EPSF  1e-5f

typedef short short8 __attribute__((ext_vector_type(8)));   // 8 bf16 (4 VGPRs)
typedef float f32x4  __attribute__((ext_vector_type(4)));

__device__ __forceinline__ uint16_t f2bf(float f) {
  uint32_t u = __float_as_uint(f);
  u += 0x7FFFu + ((u >> 16) & 1u);           // round-to-nearest-even
  return (uint16_t)(u >> 16);
}

// ===========================================================================
// Shared phase bodies (r8-verified logic, index-mapping only).
// ===========================================================================

// ---- embF repack: 256-thread team, one 64-e unit. load half ----
__device__ __forceinline__ void embF_load(const float* __restrict__ emb,
                                          int unit, int tt, uint16_t* tl) {
#pragma unroll
  for (int pass = 0; pass < 8; ++pass) {
    const int el = pass * 8 + (tt >> 5);
    const int h  = (tt & 31) * 4;
    const int eg = unit * 64 + el;
    float4 v = {0.f, 0.f, 0.f, 0.f};
    if (eg < E_DIM && eg != 0)               // padding_idx=0 -> zero row
      v = *(const float4*)(emb + (size_t)eg * HD + h);
    const uint16_t q0 = f2bf(v.x), q1 = f2bf(v.y), q2 = f2bf(v.z), q3 = f2bf(v.w);
    tl[(h + 0) * 64 + (el ^ (((h + 0) & 7) << 3))] = q0;
    tl[(h + 1) * 64 + (el ^ (((h + 1) & 7) << 3))] = q1;
    tl[(h + 2) * 64 + (el ^ (((h + 2) & 7) << 3))] = q2;
    tl[(h + 3) * 64 + (el ^ (((h + 3) & 7) << 3))] = q3;
  }
}
// ---- embF repack: store half (after block barrier) ----
__device__ __forceinline__ void embF_store(uint16_t* __restrict__ embF,
                                           int unit, int tt, const uint16_t* tl) {
  const int w = tt >> 6, lane = tt & 63;
  const int r16 = lane & 15, kgq = (lane >> 4) * 8;
  uint16_t* outp = embF + (size_t)unit * 8192 + lane * 8;
#pragma unroll
  for (int fr = 0; fr < 4; ++fr) {
    const int f  = w * 4 + fr;               // 0..15: ks=f>>3, c4=f&7
    const int h  = (f & 7) * 16 + r16;
    const int el = (f >> 3) * 32 + kgq;
    short8 d = *(const short8*)(tl + h * 64 + (el ^ ((h & 7) << 3)));
    *(short8*)(outp + f * 512) = d;
  }
}

// ---- bit-pack one row (512 threads); returns per-thread popcount ----
__device__ __forceinline__ int bitpack_row(const int* __restrict__ inp,
                                           uint8_t* __restrict__ bitsT,
                                           int r, int t) {
  const int* rp = inp + (size_t)r * E_DIM;
  int c = 0;
#pragma unroll 3
  for (int i = 0; i < 12; ++i) {
    const int idx = i * 4096 + t * 8;
    const int4 v0 = *(const int4*)(rp + idx);
    const int4 v1 = *(const int4*)(rp + idx + 4);
    const uint32_t b = (uint32_t)(v0.x == 1)        | ((uint32_t)(v0.y == 1) << 1)
                     | ((uint32_t)(v0.z == 1) << 2) | ((uint32_t)(v0.w == 1) << 3)
                     | ((uint32_t)(v1.x == 1) << 4) | ((uint32_t)(v1.y == 1) << 5)
                     | ((uint32_t)(v1.z == 1) << 6) | ((uint32_t)(v1.w == 1) << 7);
    c += __popc(b);
    const int c0 = i * 512 + t;
    bitsT[(size_t)(c0 / 56) * 28672 + r * 56 + (c0 % 56)] = (uint8_t)b;
  }
  if (t < 106) {                             // bytes 6144..6249 real
    const int idx = 49152 + t * 8;
    const int4 v0 = *(const int4*)(rp + idx);
    const int4 v1 = *(const int4*)(rp + idx + 4);
    const uint32_t b = (uint32_t)(v0.x == 1)        | ((uint32_t)(v0.y == 1) << 1)
                     | ((uint32_t)(v0.z == 1) << 2) | ((uint32_t)(v0.w == 1) << 3)
                     | ((uint32_t)(v1.x == 1) << 4) | ((uint32_t)(v1.y == 1) << 5)
                     | ((uint32_t)(v1.z == 1) << 6) | ((uint32_t)(v1.w == 1) << 7);
    c += __popc(b);
    const int c0 = 6144 + t;
    bitsT[(size_t)(c0 / 56) * 28672 + r * 56 + (c0 % 56)] = (uint8_t)b;
  } else if (t < 128) {                      // 6250..6271 zero pad
    const int c0 = 6144 + t;
    bitsT[(size_t)(c0 / 56) * 28672 + r * 56 + (c0 % 56)] = 0;
  }
  return c;
}

// ---- gemm unit (512 threads): r8-verified body, contains __syncthreads ----
__device__ __forceinline__ void gemm_unit(const uint8_t* __restrict__ bitsT,
                                          const uint16_t* __restrict__ embF,
                                          uint16_t* __restrict__ part,
                                          uint8_t* lds, int unit, int t) {
  const int lane = t & 63;
  const int w    = t >> 6;
  const int kc   = unit >> 2;
  const int ch   = unit & 3;                 // col quarter

  {
    const char* eb = (const char*)embF + (size_t)kc * 114688;
    const char* ab = (const char*)bitsT + (size_t)kc * 28672;
#define BADDR(IDX) (eb + ((IDX) >> 8) * 16384 + ((((IDX) >> 7) & 1) * 8192) \
                       + ((ch * 2 + (((IDX) >> 6) & 1)) * 1024) + ((IDX) & 63) * 16)
    uint4 b0, b1, b2, b3, a0, a1, a2, a3;
    b0 = *(const uint4*)BADDR(t);
    b1 = *(const uint4*)BADDR(512 + t);
    b2 = *(const uint4*)BADDR(1024 + t);
    a0 = *(const uint4*)(ab + t * 16);
    a1 = *(const uint4*)(ab + (512 + t) * 16);
    a2 = *(const uint4*)(ab + (1024 + t) * 16);
    if (t < 256) {
      b3 = *(const uint4*)BADDR(1536 + t);
      a3 = *(const uint4*)(ab + (1536 + t) * 16);
    }
    *(uint4*)(lds + t * 16)                  = b0;
    *(uint4*)(lds + (512 + t) * 16)          = b1;
    *(uint4*)(lds + (1024 + t) * 16)         = b2;
    *(uint4*)(lds + 28672 + t * 16)          = a0;
    *(uint4*)(lds + 28672 + (512 + t) * 16)  = a1;
    *(uint4*)(lds + 28672 + (1024 + t) * 16) = a2;
    if (t < 256) {
      *(uint4*)(lds + (1536 + t) * 16)          = b3;
      *(uint4*)(lds + 28672 + (1536 + t) * 16)  = a3;
    }
#undef BADDR
  }
  __syncthreads();

  const int r16 = lane & 15;
  const int g4  = lane >> 4;
  const int abase = 28672 + (w * 64 + r16) * 56 + g4;
  const int bbase = lane * 16;

  f32x4 acc[4][2];
#pragma unroll
  for (int rg = 0; rg < 4; ++rg)
#pragma unroll
    for (int cg = 0; cg < 2; ++cg) acc[rg][cg] = (f32x4){0.f, 0.f, 0.f, 0.f};

#define UNPACK(DST, B)                                            \
  {                                                               \
    union { uint32_t u[4]; short8 s; } x_;                        \
    x_.u[0] = ((B) & 1u) * 0x3F80u        + ((B) & 2u) * 0x1FC00000u;   \
    x_.u[1] = (((B) >> 2) & 1u) * 0x3F80u + (((B) >> 2) & 2u) * 0x1FC00000u; \
    x_.u[2] = (((B) >> 4) & 1u) * 0x3F80u + (((B) >> 4) & 2u) * 0x1FC00000u; \
    x_.u[3] = (((B) >> 6) & 1u) * 0x3F80u + (((B) >> 6) & 2u) * 0x1FC00000u; \
    DST = x_.s;                                                   \
  }

#pragma unroll
  for (int s = 0; s < NST; ++s) {
    short8 bf[2][2];
#pragma unroll
    for (int ks = 0; ks < 2; ++ks)
#pragma unroll
      for (int cg = 0; cg < 2; ++cg)
        bf[ks][cg] = *(const short8*)(lds + s * 4096 + ks * 2048 + cg * 1024 + bbase);
#pragma unroll
    for (int rg = 0; rg < 4; ++rg) {
#pragma unroll
      for (int ks = 0; ks < 2; ++ks) {
        const uint32_t b = lds[abase + rg * 896 + s * 8 + ks * 4];
        short8 af;
        UNPACK(af, b)
        acc[rg][0] = __builtin_amdgcn_mfma_f32_16x16x32_bf16(af, bf[ks][0], acc[rg][0], 0, 0, 0);
        acc[rg][1] = __builtin_amdgcn_mfma_f32_16x16x32_bf16(af, bf[ks][1], acc[rg][1], 0, 0, 0);
      }
    }
  }
#undef UNPACK

  const int jr = (lane >> 4) << 2;           // C/D: row=(l>>4)*4+j, col=l&15
#pragma unroll
  for (int rg = 0; rg < 4; ++rg)
#pragma unroll
    for (int cg = 0; cg < 2; ++cg) {
      uint16_t* pt = part + (size_t)kc * (MD * HD)
                   + (size_t)(w * 64 + rg * 16 + jr) * HD + ch * 32 + cg * 16 + r16;
#pragma unroll
      for (int j = 0; j < 4; ++j)
        pt[j * HD] = f2bf(acc[rg][cg][j]);
    }
}

// ---- fused reduce+tail for batch b (512 threads) ----
__device__ __forceinline__ void rt_block(const uint16_t* __restrict__ part,
    const float* __restrict__ cnt,
    const float* __restrict__ w1, const float* __restrict__ b1,
    const float* __restrict__ w2, const float* __restrict__ b2,
    const float* __restrict__ ln1g, const float* __restrict__ ln1b,
    const float* __restrict__ ln2g, const float* __restrict__ ln2b,
    const float* __restrict__ bn1g, const float* __restrict__ bn1b,
    const float* __restrict__ bn2g, const float* __restrict__ bn2b,
    float* __restrict__ out, uint8_t* ldsraw, int b, int t) {
  float* peL = (float*)ldsraw;               // [16][128]
  float* red = (float*)ldsraw + 2048;        // [128]
  float* sh  = (float*)ldsraw + 2176;        // [128]

  // reduce 16 rows x 128 cols over 112 kc (4 cells/thread)
#pragma unroll
  for (int i = 0; i < 4; ++i) {
    const int cell = t + i * 512;
    const int row = cell >> 7, col = cell & 127;
    const int r = b * PD + row;
    const uint16_t* pp = part + (size_t)r * HD + col;
    float s = 0.f;
#pragma unroll 4
    for (int kc = 0; kc < NKC; ++kc)
      s += __uint_as_float((uint32_t)pp[(size_t)kc * (MD * HD)] << 16);
    const float c = cnt[r];
    peL[cell] = (c > 0.f) ? (s / c) : 0.f;
  }
  __syncthreads();

  const bool act = (t < 128);
  float x = 0.f;
  if (act) {
#pragma unroll
    for (int p = 0; p < PD; ++p) x += peL[p * HD + t];
    x *= (1.f / PD);
  }
  const float bninv = rsqrtf(1.f + EPSF);

  // ---- LN1 ----
  if (act) red[t] = x;
  __syncthreads();
  for (int o = 64; o > 0; o >>= 1) { if (t < o) red[t] += red[t + o]; __syncthreads(); }
  const float mu1 = red[0] * (1.f / HD); __syncthreads();
  const float d1 = x - mu1;
  if (act) red[t] = d1 * d1;
  __syncthreads();
  for (int o = 64; o > 0; o >>= 1) { if (t < o) red[t] += red[t + o]; __syncthreads(); }
  const float v1 = red[0] * (1.f / HD); __syncthreads();

  // ---- FC1 + ReLU + BN1 ----
  if (act) sh[t] = ln1g[t] * d1 * rsqrtf(v1 + EPSF) + ln1b[t];
  __syncthreads();
  float a = 0.f;
  if (act) {
    a = b1[t];
    const float4* wrow1 = (const float4*)(w1 + (size_t)t * HD);
#pragma unroll 8
    for (int k = 0; k < 32; ++k) {
      const float4 w = wrow1[k];
      a += w.x * sh[k * 4] + w.y * sh[k * 4 + 1] + w.z * sh[k * 4 + 2] + w.w * sh[k * 4 + 3];
    }
    a = fmaxf(a, 0.f);
    a = bn1g[t] * a * bninv + bn1b[t];
  }
  __syncthreads();

  // ---- LN2 ----
  if (act) red[t] = a;
  __syncthreads();
  for (int o = 64; o > 0; o >>= 1) { if (t < o) red[t] += red[t + o]; __syncthreads(); }
  const float mu2 = red[0] * (1.f / HD); __syncthreads();
  const float d2 = a - mu2;
  if (act) red[t] = d2 * d2;
  __syncthreads();
  for (int o = 64; o > 0; o >>= 1) { if (t < o) red[t] += red[t + o]; __syncthreads(); }
  const float v2 = red[0] * (1.f / HD); __syncthreads();

  // ---- FC2 + ReLU + BN2 ----
  if (act) sh[t] = ln2g[t] * d2 * rsqrtf(v2 + EPSF) + ln2b[t];
  __syncthreads();
  if (act) {
    float a2 = b2[t];
    const float4* wrow2 = (const float4*)(w2 + (size_t)t * HD);
#pragma unroll 8
    for (int k = 0; k < 32; ++k) {
      const float4 w = wrow2[k];
      a2 += w.x * sh[k * 4] + w.y * sh[k * 4 + 1] + w.z * sh[k * 4 + 2] + w.w * sh[k * 4 + 3];
    }
    a2 = fmaxf(a2, 0.f);
    a2 = bn2g[t] * a2 * bninv + bn2b[t];
    out[b * HD + t] = a2;
  }
}

// ---- prep phase body (one block's share): embF 2 team-units + 2 bitpack rows
__device__ __forceinline__ void prep_block(const int* __restrict__ inp,
                                           const float* __restrict__ emb,
                                           uint8_t* __restrict__ bitsT,
                                           uint16_t* __restrict__ embF,
                                           float* __restrict__ cnt,
                                           uint8_t* lds, int* sc, int bid, int t) {
  const int team = t >> 8, tt = t & 255;
  uint16_t* tl = (uint16_t*)(lds + team * 16384);
  const int slot = bid * 2 + team;           // 0..511
  embF_load(emb, slot, tt, tl);              // slot < 784 always
  __syncthreads();
  embF_store(embF, slot, tt, tl);
  __syncthreads();
  if (slot + 512 < NEB) embF_load(emb, slot + 512, tt, tl);
  __syncthreads();
  if (slot + 512 < NEB) embF_store(embF, slot + 512, tt, tl);

  for (int rr = 0; rr < 2; ++rr) {
    const int r = bid * 2 + rr;
    int c = bitpack_row(inp, bitsT, r, t);
#pragma unroll
    for (int o = 1; o < 64; o <<= 1) c += __shfl_xor(c, o);
    if ((t & 63) == 0) sc[t >> 6] = c;
    __syncthreads();
    if (t == 0) {
      int s = 0;
#pragma unroll
      for (int i = 0; i < 8; ++i) s += sc[i];
      cnt[r] = (float)s;
    }
    __syncthreads();
  }
}

// ---- gemm phase body (one block's share): units bid and bid+256 ----
__device__ __forceinline__ void gemm_block(const uint8_t* __restrict__ bitsT,
                                           const uint16_t* __restrict__ embF,
                                           uint16_t* __restrict__ part,
                                           uint8_t* lds, int bid, int t) {
  gemm_unit(bitsT, embF, part, lds, bid, t);
  if (bid + GRID < NKC * 4) {
    __syncthreads();                         // drain LDS reads of unit 1
    gemm_unit(bitsT, embF, part, lds, bid + GRID, t);
  }
}

// ===========================================================================
// Cooperative all-in-one kernel (256 blocks x 512 thr, 1 block/CU).
// ===========================================================================
__global__ __launch_bounds__(512, 2) void k_all(
    const int* __restrict__ inp, const float* __restrict__ emb,
    const float* __restrict__ w1, const float* __restrict__ b1,
    const float* __restrict__ w2, const float* __restrict__ b2,
    const float* __restrict__ ln1g, const float* __restrict__ ln1b,
    const float* __restrict__ ln2g, const float* __restrict__ ln2b,
    const float* __restrict__ bn1g, const float* __restrict__ bn1b,
    const float* __restrict__ bn2g, const float* __restrict__ bn2b,
    uint8_t* __restrict__ bitsT, uint16_t* __restrict__ embF,
    uint16_t* __restrict__ part, float* __restrict__ cnt,
    float* __restrict__ out) {
  __shared__ __align__(16) uint8_t lds[57344];
  __shared__ int sc[8];
  const int t   = threadIdx.x;
  const int bid = blockIdx.x;
  cg::grid_group grid = cg::this_grid();

  prep_block(inp, emb, bitsT, embF, cnt, lds, sc, bid, t);
  grid.sync();
  gemm_block(bitsT, embF, part, lds, bid, t);
  grid.sync();
  if (bid < BD)
    rt_block(part, cnt, w1, b1, w2, b2, ln1g, ln1b, ln2g, ln2b,
             bn1g, bn1b, bn2g, bn2b, out, lds, bid, t);
}

// ===========================================================================
// Fallback: identical phase bodies as 3 plain kernels.
// ===========================================================================
__global__ __launch_bounds__(512, 2) void k_p(const int* __restrict__ inp,
                                              const float* __restrict__ emb,
                                              uint8_t* __restrict__ bitsT,
                                              uint16_t* __restrict__ embF,
                                              float* __restrict__ cnt) {
  __shared__ __align__(16) uint8_t lds[57344];
  __shared__ int sc[8];
  prep_block(inp, emb, bitsT, embF, cnt, lds, sc, blockIdx.x, threadIdx.x);
}

__global__ __launch_bounds__(512, 2) void k_g(const uint8_t* __restrict__ bitsT,
                                              const uint16_t* __restrict__ embF,
                                              uint16_t* __restrict__ part) {
  __shared__ __align__(16) uint8_t lds[57344];
  gemm_block(bitsT, embF, part, lds, blockIdx.x, threadIdx.x);
}

__global__ __launch_bounds__(512, 2) void k_rt(const uint16_t* __restrict__ part,
    const float* __restrict__ cnt,
    const float* __restrict__ w1, const float* __restrict__ b1,
    const float* __restrict__ w2, const float* __restrict__ b2,
    const float* __restrict__ ln1g, const float* __restrict__ ln1b,
    const float* __restrict__ ln2g, const float* __restrict__ ln2b,
    const float* __restrict__ bn1g, const float* __restrict__ bn1b,
    const float* __restrict__ bn2g, const float* __restrict__ bn2b,
    float* __restrict__ out) {
  __shared__ __align__(16) uint8_t lds[57344];
  rt_block(part, cnt, w1, b1, w2, b2, ln1g, ln1b, ln2g, ln2b,
           bn1g, bn1b, bn2g, bn2b, out, lds, blockIdx.x, threadIdx.x);
}

// ---------------------------------------------------------------------------
extern "C" void kernel_launch(void* const* d_in, const int* in_sizes, int n_in,
                              void* d_out, int out_size, void* d_ws, size_t ws_size,
                              hipStream_t stream) {
  const int*   inp  = (const int*)d_in[0];
  const float* emb  = (const float*)d_in[1];
  const float* w1   = (const float*)d_in[2];
  const float* b1   = (const float*)d_in[3];
  const float* w2   = (const float*)d_in[4];
  const float* b2   = (const float*)d_in[5];
  const float* ln1g = (const float*)d_in[6];
  const float* ln1b = (const float*)d_in[7];
  const float* ln2g = (const float*)d_in[8];
  const float* ln2b = (const float*)d_in[9];
  const float* bn1g = (const float*)d_in[10];
  const float* bn1b = (const float*)d_in[11];
  const float* bn2g = (const float*)d_in[12];
  const float* bn2b = (const float*)d_in[13];
  float* out = (float*)d_out;

  // workspace layout (30.7 MB total)
  char* ws = (char*)d_ws;
  uint8_t*  bitsT = (uint8_t*)ws;                          // 112*512*56 = 3,211,264 (+64 pad)
  uint16_t* embF  = (uint16_t*)(ws + 3211328);             // 784*16384  = 12,845,056
  uint16_t* part  = (uint16_t*)(ws + 3211328 + 12845056);  // 112*512*128*2 = 14,680,064
  float*    cnt   = (float*)(ws + 3211328 + 12845056 + 14680064);   // 2,048

  void* args[] = {
    (void*)&inp, (void*)&emb, (void*)&w1, (void*)&b1, (void*)&w2, (void*)&b2,
    (void*)&ln1g, (void*)&ln1b, (void*)&ln2g, (void*)&ln2b,
    (void*)&bn1g, (void*)&bn1b, (void*)&bn2g, (void*)&bn2b,
    (void*)&bitsT, (void*)&embF, (void*)&part, (void*)&cnt, (void*)&out
  };
  hipError_t err = hipLaunchCooperativeKernel((const void*)k_all, dim3(GRID),
                                              dim3(512), args, 0, stream);
  if (err != hipSuccess) {
    // deterministic fallback: same phase bodies, 3 plain launches
    k_p<<<GRID, 512, 0, stream>>>(inp, emb, bitsT, embF, cnt);
    k_g<<<GRID, 512, 0, stream>>>(bitsT, embF, part);
    k_rt<<<BD, 512, 0, stream>>>(part, cnt, w1, b1, w2, b2,
                                 ln1g, ln1b, ln2g, ln2b,
                                 bn1g, bn1b, bn2g, bn2b, out);
  }
}

// Round 11
// 84.695 us; speedup vs baseline: 1.9922x; 1.9922x over previous
//
#include <hip/hip_runtime.h>
#include <stdint.h>

// Problem: B=32, P=16, E=50000, H=128
#define E_DIM 50000
#define EP2   50176          // padded: 112 * 448 = 784 * 64
#define HD    128
#define BD    32
#define PD    16
#define MD    512            // B*P
#define KCHUNK 448           // 7 stages of 64
#define NKC   112            // EP2 / KCHUNK exactly
#define NST   7
#define NEB   784            // embF 64-e stages = EP2/64
#define EPSF  1e-5f

typedef short short8 __attribute__((ext_vector_type(8)));   // 8 bf16 (4 VGPRs)
typedef float f32x4  __attribute__((ext_vector_type(4)));

__device__ __forceinline__ uint16_t f2bf(float f) {
  uint32_t u = __float_as_uint(f);
  u += 0x7FFFu + ((u >> 16) & 1u);           // round-to-nearest-even
  return (uint16_t)(u >> 16);
}

// ---------------------------------------------------------------------------
// Kernel 1 (fused prep) — identical to round 8 (verified).
// ---------------------------------------------------------------------------
__global__ __launch_bounds__(256) void k_prep(const float* __restrict__ emb,
                                              const int* __restrict__ inp,
                                              uint16_t* __restrict__ embF,
                                              uint8_t* __restrict__ bitsT,
                                              float* __restrict__ cnt) {
  __shared__ __align__(16) uint16_t lds[HD * 64];
  __shared__ int sc[4];
  const int t = threadIdx.x;

  if (blockIdx.x < NEB) {
    // ---- embF repack ----
    const int e0 = blockIdx.x * 64;
#pragma unroll
    for (int pass = 0; pass < 8; ++pass) {
      const int el = pass * 8 + (t >> 5);
      const int h  = (t & 31) * 4;
      const int eg = e0 + el;
      float4 v = {0.f, 0.f, 0.f, 0.f};
      if (eg < E_DIM && eg != 0)
        v = *(const float4*)(emb + (size_t)eg * HD + h);
      const uint16_t q0 = f2bf(v.x), q1 = f2bf(v.y), q2 = f2bf(v.z), q3 = f2bf(v.w);
      lds[(h + 0) * 64 + (el ^ (((h + 0) & 7) << 3))] = q0;
      lds[(h + 1) * 64 + (el ^ (((h + 1) & 7) << 3))] = q1;
      lds[(h + 2) * 64 + (el ^ (((h + 2) & 7) << 3))] = q2;
      lds[(h + 3) * 64 + (el ^ (((h + 3) & 7) << 3))] = q3;
    }
    __syncthreads();
    const int w    = t >> 6;
    const int lane = t & 63;
    const int r16  = lane & 15;
    const int kgq  = (lane >> 4) * 8;
    uint16_t* outp = embF + (size_t)blockIdx.x * 8192 + lane * 8;
#pragma unroll
    for (int fr = 0; fr < 4; ++fr) {
      const int f  = w * 4 + fr;               // 0..15: ks=f>>3, c4=f&7
      const int h  = (f & 7) * 16 + r16;
      const int el = (f >> 3) * 32 + kgq;
      short8 d = *(const short8*)(lds + h * 64 + (el ^ ((h & 7) << 3)));
      *(short8*)(outp + f * 512) = d;
    }
  } else {
    // ---- bit-pack one row into kc-major bitsT ----
    const int r = blockIdx.x - NEB;
    const int* rp = inp + (size_t)r * E_DIM;
    int c = 0;
#pragma unroll 3
    for (int i = 0; i < 24; ++i) {
      const int idx = i * 2048 + t * 8;
      const int4 v0 = *(const int4*)(rp + idx);
      const int4 v1 = *(const int4*)(rp + idx + 4);
      const uint32_t b = (uint32_t)(v0.x == 1)        | ((uint32_t)(v0.y == 1) << 1)
                       | ((uint32_t)(v0.z == 1) << 2) | ((uint32_t)(v0.w == 1) << 3)
                       | ((uint32_t)(v1.x == 1) << 4) | ((uint32_t)(v1.y == 1) << 5)
                       | ((uint32_t)(v1.z == 1) << 6) | ((uint32_t)(v1.w == 1) << 7);
      c += __popc(b);
      const int c0 = i * 256 + t;
      bitsT[(size_t)(c0 / 56) * 28672 + r * 56 + (c0 % 56)] = (uint8_t)b;
    }
    if (t < 106) {
      const int idx = 49152 + t * 8;
      const int4 v0 = *(const int4*)(rp + idx);
      const int4 v1 = *(const int4*)(rp + idx + 4);
      const uint32_t b = (uint32_t)(v0.x == 1)        | ((uint32_t)(v0.y == 1) << 1)
                       | ((uint32_t)(v0.z == 1) << 2) | ((uint32_t)(v0.w == 1) << 3)
                       | ((uint32_t)(v1.x == 1) << 4) | ((uint32_t)(v1.y == 1) << 5)
                       | ((uint32_t)(v1.z == 1) << 6) | ((uint32_t)(v1.w == 1) << 7);
      c += __popc(b);
      const int c0 = 6144 + t;
      bitsT[(size_t)(c0 / 56) * 28672 + r * 56 + (c0 % 56)] = (uint8_t)b;
    } else if (t < 128) {
      const int c0 = 6144 + t;
      bitsT[(size_t)(c0 / 56) * 28672 + r * 56 + (c0 % 56)] = 0;
    }
#pragma unroll
    for (int o = 1; o < 64; o <<= 1) c += __shfl_xor(c, o);
    if ((t & 63) == 0) sc[t >> 6] = c;
    __syncthreads();
    if (t == 0) cnt[r] = (float)(sc[0] + sc[1] + sc[2] + sc[3]);
  }
}

// ---------------------------------------------------------------------------
// Kernel 2 — identical to round 8 (verified).
// ---------------------------------------------------------------------------
__global__ __launch_bounds__(512, 4) void k_gemm(const uint8_t* __restrict__ bitsT,
                                                 const uint16_t* __restrict__ embF,
                                                 uint16_t* __restrict__ part) {
  __shared__ __align__(16) uint8_t lds[57344];   // [0,28672): B frags, [28672,..): A bits

  const int t    = threadIdx.x;
  const int lane = t & 63;
  const int w    = t >> 6;
  const int kc   = blockIdx.x >> 2;
  const int ch   = blockIdx.x & 3;               // col quarter

  {
    const char* eb = (const char*)embF + (size_t)kc * 114688;
    const char* ab = (const char*)bitsT + (size_t)kc * 28672;
#define BADDR(IDX) (eb + ((IDX) >> 8) * 16384 + ((((IDX) >> 7) & 1) * 8192) \
                       + ((ch * 2 + (((IDX) >> 6) & 1)) * 1024) + ((IDX) & 63) * 16)
    uint4 b0, b1, b2, b3, a0, a1, a2, a3;
    b0 = *(const uint4*)BADDR(t);
    b1 = *(const uint4*)BADDR(512 + t);
    b2 = *(const uint4*)BADDR(1024 + t);
    a0 = *(const uint4*)(ab + t * 16);
    a1 = *(const uint4*)(ab + (512 + t) * 16);
    a2 = *(const uint4*)(ab + (1024 + t) * 16);
    if (t < 256) {
      b3 = *(const uint4*)BADDR(1536 + t);
      a3 = *(const uint4*)(ab + (1536 + t) * 16);
    }
    *(uint4*)(lds + t * 16)                  = b0;
    *(uint4*)(lds + (512 + t) * 16)          = b1;
    *(uint4*)(lds + (1024 + t) * 16)         = b2;
    *(uint4*)(lds + 28672 + t * 16)          = a0;
    *(uint4*)(lds + 28672 + (512 + t) * 16)  = a1;
    *(uint4*)(lds + 28672 + (1024 + t) * 16) = a2;
    if (t < 256) {
      *(uint4*)(lds + (1536 + t) * 16)          = b3;
      *(uint4*)(lds + 28672 + (1536 + t) * 16)  = a3;
    }
#undef BADDR
  }
  __syncthreads();

  const int r16 = lane & 15;
  const int g4  = lane >> 4;
  const int abase = 28672 + (w * 64 + r16) * 56 + g4;
  const int bbase = lane * 16;

  f32x4 acc[4][2];
#pragma unroll
  for (int rg = 0; rg < 4; ++rg)
#pragma unroll
    for (int cg = 0; cg < 2; ++cg) acc[rg][cg] = (f32x4){0.f, 0.f, 0.f, 0.f};

#define UNPACK(DST, B)                                            \
  {                                                               \
    union { uint32_t u[4]; short8 s; } x_;                        \
    x_.u[0] = ((B) & 1u) * 0x3F80u        + ((B) & 2u) * 0x1FC00000u;   \
    x_.u[1] = (((B) >> 2) & 1u) * 0x3F80u + (((B) >> 2) & 2u) * 0x1FC00000u; \
    x_.u[2] = (((B) >> 4) & 1u) * 0x3F80u + (((B) >> 4) & 2u) * 0x1FC00000u; \
    x_.u[3] = (((B) >> 6) & 1u) * 0x3F80u + (((B) >> 6) & 2u) * 0x1FC00000u; \
    DST = x_.s;                                                   \
  }

#pragma unroll
  for (int s = 0; s < NST; ++s) {
    short8 bf[2][2];
#pragma unroll
    for (int ks = 0; ks < 2; ++ks)
#pragma unroll
      for (int cg = 0; cg < 2; ++cg)
        bf[ks][cg] = *(const short8*)(lds + s * 4096 + ks * 2048 + cg * 1024 + bbase);
#pragma unroll
    for (int rg = 0; rg < 4; ++rg) {
#pragma unroll
      for (int ks = 0; ks < 2; ++ks) {
        const uint32_t b = lds[abase + rg * 896 + s * 8 + ks * 4];
        short8 af;
        UNPACK(af, b)
        acc[rg][0] = __builtin_amdgcn_mfma_f32_16x16x32_bf16(af, bf[ks][0], acc[rg][0], 0, 0, 0);
        acc[rg][1] = __builtin_amdgcn_mfma_f32_16x16x32_bf16(af, bf[ks][1], acc[rg][1], 0, 0, 0);
      }
    }
  }
#undef UNPACK

  const int jr = (lane >> 4) << 2;                 // C/D: row=(l>>4)*4+j, col=l&15
#pragma unroll
  for (int rg = 0; rg < 4; ++rg)
#pragma unroll
    for (int cg = 0; cg < 2; ++cg) {
      uint16_t* pt = part + (size_t)kc * (MD * HD)
                   + (size_t)(w * 64 + rg * 16 + jr) * HD + ch * 32 + cg * 16 + r16;
#pragma unroll
      for (int j = 0; j < 4; ++j)
        pt[j * HD] = f2bf(acc[rg][cg][j]);
    }
}

// ---------------------------------------------------------------------------
// Kernel 3 — identical to round 8 (verified).
// ---------------------------------------------------------------------------
__global__ __launch_bounds__(512) void k_reduce(const uint16_t* __restrict__ part,
                                                const float* __restrict__ cnt,
                                                float* __restrict__ pe) {
  __shared__ float red[512];
  const int r   = blockIdx.x;
  const int t   = threadIdx.x;
  const int col = t & 127;
  const int sub = t >> 7;
  const uint16_t* pp = part + (size_t)(sub * 28) * (MD * HD) + (size_t)r * HD + col;
  float s = 0.f;
#pragma unroll
  for (int i = 0; i < 28; ++i)
    s += __uint_as_float((uint32_t)pp[(size_t)i * (MD * HD)] << 16);
  red[t] = s;
  __syncthreads();
  if (t < 128) {
    const float tot = red[t] + red[t + 128] + red[t + 256] + red[t + 384];
    const float c   = cnt[r];
    pe[r * HD + t] = (c > 0.f) ? (tot / c) : 0.f;
  }
}

// ---------------------------------------------------------------------------
// Kernel 4 — identical to round 8 (verified).
// ---------------------------------------------------------------------------
__global__ __launch_bounds__(128) void k_tail(
    const float* __restrict__ pe,
    const float* __restrict__ w1, const float* __restrict__ b1,
    const float* __restrict__ w2, const float* __restrict__ b2,
    const float* __restrict__ ln1g, const float* __restrict__ ln1b,
    const float* __restrict__ ln2g, const float* __restrict__ ln2b,
    const float* __restrict__ bn1g, const float* __restrict__ bn1b,
    const float* __restrict__ bn2g, const float* __restrict__ bn2b,
    float* __restrict__ out) {
  const int b = blockIdx.x, t = threadIdx.x;
  __shared__ float sh[HD];
  __shared__ float red[HD];

  float x = 0.f;
#pragma unroll
  for (int p = 0; p < PD; ++p) x += pe[(b * PD + p) * HD + t];
  x *= (1.f / PD);

  const float bninv = rsqrtf(1.f + EPSF);

  // ---- LN1 ----
  red[t] = x; __syncthreads();
  for (int o = 64; o > 0; o >>= 1) { if (t < o) red[t] += red[t + o]; __syncthreads(); }
  const float mu1 = red[0] * (1.f / HD); __syncthreads();
  const float d1 = x - mu1;
  red[t] = d1 * d1; __syncthreads();
  for (int o = 64; o > 0; o >>= 1) { if (t < o) red[t] += red[t + o]; __syncthreads(); }
  const float v1 = red[0] * (1.f / HD); __syncthreads();
  const float y1 = ln1g[t] * d1 * rsqrtf(v1 + EPSF) + ln1b[t];

  // ---- FC1 + ReLU + BN1 ----
  sh[t] = y1; __syncthreads();
  float a = b1[t];
  const float4* wrow1 = (const float4*)(w1 + (size_t)t * HD);
#pragma unroll 8
  for (int k = 0; k < 32; ++k) {
    const float4 w = wrow1[k];
    a += w.x * sh[k * 4] + w.y * sh[k * 4 + 1] + w.z * sh[k * 4 + 2] + w.w * sh[k * 4 + 3];
  }
  a = fmaxf(a, 0.f);
  a = bn1g[t] * a * bninv + bn1b[t];
  __syncthreads();

  // ---- LN2 ----
  red[t] = a; __syncthreads();
  for (int o = 64; o > 0; o >>= 1) { if (t < o) red[t] += red[t + o]; __syncthreads(); }
  const float mu2 = red[0] * (1.f / HD); __syncthreads();
  const float d2 = a - mu2;
  red[t] = d2 * d2; __syncthreads();
  for (int o = 64; o > 0; o >>= 1) { if (t < o) red[t] += red[t + o]; __syncthreads(); }
  const float v2 = red[0] * (1.f / HD); __syncthreads();
  const float y2 = ln2g[t] * d2 * rsqrtf(v2 + EPSF) + ln2b[t];

  // ---- FC2 + ReLU + BN2 ----
  sh[t] = y2; __syncthreads();
  float a2 = b2[t];
  const float4* wrow2 = (const float4*)(w2 + (size_t)t * HD);
#pragma unroll 8
  for (int k = 0; k < 32; ++k) {
    const float4 w = wrow2[k];
    a2 += w.x * sh[k * 4] + w.y * sh[k * 4 + 1] + w.z * sh[k * 4 + 2] + w.w * sh[k * 4 + 3];
  }
  a2 = fmaxf(a2, 0.f);
  a2 = bn2g[t] * a2 * bninv + bn2b[t];
  out[b * HD + t] = a2;
}

// ---------------------------------------------------------------------------
// ATTRIBUTION EXPERIMENT: k_prep launched TWICE (idempotent — bitsT/embF/cnt
// written identically both times). N = 62.0 + (prep + boundary).
// Hyp K (prep-dominant): N ~ 90-100.  Hyp B (boundary-dominant): N ~ 70-76.
// ---------------------------------------------------------------------------
extern "C" void kernel_launch(void* const* d_in, const int* in_sizes, int n_in,
                              void* d_out, int out_size, void* d_ws, size_t ws_size,
                              hipStream_t stream) {
  const int*   inp  = (const int*)d_in[0];
  const float* emb  = (const float*)d_in[1];
  const float* w1   = (const float*)d_in[2];
  const float* b1   = (const float*)d_in[3];
  const float* w2   = (const float*)d_in[4];
  const float* b2   = (const float*)d_in[5];
  const float* ln1g = (const float*)d_in[6];
  const float* ln1b = (const float*)d_in[7];
  const float* ln2g = (const float*)d_in[8];
  const float* ln2b = (const float*)d_in[9];
  const float* bn1g = (const float*)d_in[10];
  const float* bn1b = (const float*)d_in[11];
  const float* bn2g = (const float*)d_in[12];
  const float* bn2b = (const float*)d_in[13];
  float* out = (float*)d_out;

  // workspace layout (31.0 MB total)
  char* ws = (char*)d_ws;
  uint8_t*  bitsT = (uint8_t*)ws;                          // 112*512*56 = 3,211,264 (+64 pad)
  uint16_t* embF  = (uint16_t*)(ws + 3211328);             // 784*16384  = 12,845,056
  uint16_t* part  = (uint16_t*)(ws + 3211328 + 12845056);  // 112*512*128*2 = 14,680,064
  float*    cnt   = (float*)(ws + 3211328 + 12845056 + 14680064);          // 2,048
  float*    pe    = (float*)(ws + 3211328 + 12845056 + 14680064 + 2048);   // 262,144

  k_prep<<<NEB + MD, 256, 0, stream>>>(emb, inp, embF, bitsT, cnt);
  k_prep<<<NEB + MD, 256, 0, stream>>>(emb, inp, embF, bitsT, cnt);   // duplicate (measurement)
  k_gemm<<<NKC * 4, 512, 0, stream>>>(bitsT, embF, part);
  k_reduce<<<MD, 512, 0, stream>>>(part, cnt, pe);
  k_tail<<<BD, 128, 0, stream>>>(pe, w1, b1, w2, b2, ln1g, ln1b, ln2g, ln2b,
                                 bn1g, bn1b, bn2g, bn2b, out);
}

// Round 12
// 80.866 us; speedup vs baseline: 2.0865x; 1.0474x over previous
//
#include <hip/hip_runtime.h>
#include <stdint.h>

// Problem: B=32, P=16, E=50000, H=128
#define E_DIM 50000
#define EP2   50176          // padded: 112 * 448 = 784 * 64
#define HD    128
#define BD    32
#define PD    16
#define MD    512            // B*P
#define KCHUNK 448           // 7 stages of 64
#define NKC   112            // EP2 / KCHUNK exactly
#define NST   7
#define NEB   784            // embF 64-e stages = EP2/64
#define EPSF  1e-5f

typedef short short8 __attribute__((ext_vector_type(8)));   // 8 bf16 (4 VGPRs)
typedef float f32x4  __attribute__((ext_vector_type(4)));

__device__ __forceinline__ uint16_t f2bf(float f) {
  uint32_t u = __float_as_uint(f);
  u += 0x7FFFu + ((u >> 16) & 1u);           // round-to-nearest-even
  return (uint16_t)(u >> 16);
}

// ---------------------------------------------------------------------------
// Kernel 1 (fused prep) — identical to round 8 (verified).
// ---------------------------------------------------------------------------
__global__ __launch_bounds__(256) void k_prep(const float* __restrict__ emb,
                                              const int* __restrict__ inp,
                                              uint16_t* __restrict__ embF,
                                              uint8_t* __restrict__ bitsT,
                                              float* __restrict__ cnt) {
  __shared__ __align__(16) uint16_t lds[HD * 64];
  __shared__ int sc[4];
  const int t = threadIdx.x;

  if (blockIdx.x < NEB) {
    // ---- embF repack ----
    const int e0 = blockIdx.x * 64;
#pragma unroll
    for (int pass = 0; pass < 8; ++pass) {
      const int el = pass * 8 + (t >> 5);
      const int h  = (t & 31) * 4;
      const int eg = e0 + el;
      float4 v = {0.f, 0.f, 0.f, 0.f};
      if (eg < E_DIM && eg != 0)
        v = *(const float4*)(emb + (size_t)eg * HD + h);
      const uint16_t q0 = f2bf(v.x), q1 = f2bf(v.y), q2 = f2bf(v.z), q3 = f2bf(v.w);
      lds[(h + 0) * 64 + (el ^ (((h + 0) & 7) << 3))] = q0;
      lds[(h + 1) * 64 + (el ^ (((h + 1) & 7) << 3))] = q1;
      lds[(h + 2) * 64 + (el ^ (((h + 2) & 7) << 3))] = q2;
      lds[(h + 3) * 64 + (el ^ (((h + 3) & 7) << 3))] = q3;
    }
    __syncthreads();
    const int w    = t >> 6;
    const int lane = t & 63;
    const int r16  = lane & 15;
    const int kgq  = (lane >> 4) * 8;
    uint16_t* outp = embF + (size_t)blockIdx.x * 8192 + lane * 8;
#pragma unroll
    for (int fr = 0; fr < 4; ++fr) {
      const int f  = w * 4 + fr;               // 0..15: ks=f>>3, c4=f&7
      const int h  = (f & 7) * 16 + r16;
      const int el = (f >> 3) * 32 + kgq;
      short8 d = *(const short8*)(lds + h * 64 + (el ^ ((h & 7) << 3)));
      *(short8*)(outp + f * 512) = d;
    }
  } else {
    // ---- bit-pack one row into kc-major bitsT ----
    const int r = blockIdx.x - NEB;
    const int* rp = inp + (size_t)r * E_DIM;
    int c = 0;
#pragma unroll 3
    for (int i = 0; i < 24; ++i) {
      const int idx = i * 2048 + t * 8;
      const int4 v0 = *(const int4*)(rp + idx);
      const int4 v1 = *(const int4*)(rp + idx + 4);
      const uint32_t b = (uint32_t)(v0.x == 1)        | ((uint32_t)(v0.y == 1) << 1)
                       | ((uint32_t)(v0.z == 1) << 2) | ((uint32_t)(v0.w == 1) << 3)
                       | ((uint32_t)(v1.x == 1) << 4) | ((uint32_t)(v1.y == 1) << 5)
                       | ((uint32_t)(v1.z == 1) << 6) | ((uint32_t)(v1.w == 1) << 7);
      c += __popc(b);
      const int c0 = i * 256 + t;
      bitsT[(size_t)(c0 / 56) * 28672 + r * 56 + (c0 % 56)] = (uint8_t)b;
    }
    if (t < 106) {
      const int idx = 49152 + t * 8;
      const int4 v0 = *(const int4*)(rp + idx);
      const int4 v1 = *(const int4*)(rp + idx + 4);
      const uint32_t b = (uint32_t)(v0.x == 1)        | ((uint32_t)(v0.y == 1) << 1)
                       | ((uint32_t)(v0.z == 1) << 2) | ((uint32_t)(v0.w == 1) << 3)
                       | ((uint32_t)(v1.x == 1) << 4) | ((uint32_t)(v1.y == 1) << 5)
                       | ((uint32_t)(v1.z == 1) << 6) | ((uint32_t)(v1.w == 1) << 7);
      c += __popc(b);
      const int c0 = 6144 + t;
      bitsT[(size_t)(c0 / 56) * 28672 + r * 56 + (c0 % 56)] = (uint8_t)b;
    } else if (t < 128) {
      const int c0 = 6144 + t;
      bitsT[(size_t)(c0 / 56) * 28672 + r * 56 + (c0 % 56)] = 0;
    }
#pragma unroll
    for (int o = 1; o < 64; o <<= 1) c += __shfl_xor(c, o);
    if ((t & 63) == 0) sc[t >> 6] = c;
    __syncthreads();
    if (t == 0) cnt[r] = (float)(sc[0] + sc[1] + sc[2] + sc[3]);
  }
}

// ---------------------------------------------------------------------------
// Kernel 2 — identical to round 8 (verified).
// ---------------------------------------------------------------------------
__global__ __launch_bounds__(512, 4) void k_gemm(const uint8_t* __restrict__ bitsT,
                                                 const uint16_t* __restrict__ embF,
                                                 uint16_t* __restrict__ part) {
  __shared__ __align__(16) uint8_t lds[57344];   // [0,28672): B frags, [28672,..): A bits

  const int t    = threadIdx.x;
  const int lane = t & 63;
  const int w    = t >> 6;
  const int kc   = blockIdx.x >> 2;
  const int ch   = blockIdx.x & 3;               // col quarter

  {
    const char* eb = (const char*)embF + (size_t)kc * 114688;
    const char* ab = (const char*)bitsT + (size_t)kc * 28672;
#define BADDR(IDX) (eb + ((IDX) >> 8) * 16384 + ((((IDX) >> 7) & 1) * 8192) \
                       + ((ch * 2 + (((IDX) >> 6) & 1)) * 1024) + ((IDX) & 63) * 16)
    uint4 b0, b1, b2, b3, a0, a1, a2, a3;
    b0 = *(const uint4*)BADDR(t);
    b1 = *(const uint4*)BADDR(512 + t);
    b2 = *(const uint4*)BADDR(1024 + t);
    a0 = *(const uint4*)(ab + t * 16);
    a1 = *(const uint4*)(ab + (512 + t) * 16);
    a2 = *(const uint4*)(ab + (1024 + t) * 16);
    if (t < 256) {
      b3 = *(const uint4*)BADDR(1536 + t);
      a3 = *(const uint4*)(ab + (1536 + t) * 16);
    }
    *(uint4*)(lds + t * 16)                  = b0;
    *(uint4*)(lds + (512 + t) * 16)          = b1;
    *(uint4*)(lds + (1024 + t) * 16)         = b2;
    *(uint4*)(lds + 28672 + t * 16)          = a0;
    *(uint4*)(lds + 28672 + (512 + t) * 16)  = a1;
    *(uint4*)(lds + 28672 + (1024 + t) * 16) = a2;
    if (t < 256) {
      *(uint4*)(lds + (1536 + t) * 16)          = b3;
      *(uint4*)(lds + 28672 + (1536 + t) * 16)  = a3;
    }
#undef BADDR
  }
  __syncthreads();

  const int r16 = lane & 15;
  const int g4  = lane >> 4;
  const int abase = 28672 + (w * 64 + r16) * 56 + g4;
  const int bbase = lane * 16;

  f32x4 acc[4][2];
#pragma unroll
  for (int rg = 0; rg < 4; ++rg)
#pragma unroll
    for (int cg = 0; cg < 2; ++cg) acc[rg][cg] = (f32x4){0.f, 0.f, 0.f, 0.f};

#define UNPACK(DST, B)                                            \
  {                                                               \
    union { uint32_t u[4]; short8 s; } x_;                        \
    x_.u[0] = ((B) & 1u) * 0x3F80u        + ((B) & 2u) * 0x1FC00000u;   \
    x_.u[1] = (((B) >> 2) & 1u) * 0x3F80u + (((B) >> 2) & 2u) * 0x1FC00000u; \
    x_.u[2] = (((B) >> 4) & 1u) * 0x3F80u + (((B) >> 4) & 2u) * 0x1FC00000u; \
    x_.u[3] = (((B) >> 6) & 1u) * 0x3F80u + (((B) >> 6) & 2u) * 0x1FC00000u; \
    DST = x_.s;                                                   \
  }

#pragma unroll
  for (int s = 0; s < NST; ++s) {
    short8 bf[2][2];
#pragma unroll
    for (int ks = 0; ks < 2; ++ks)
#pragma unroll
      for (int cg = 0; cg < 2; ++cg)
        bf[ks][cg] = *(const short8*)(lds + s * 4096 + ks * 2048 + cg * 1024 + bbase);
#pragma unroll
    for (int rg = 0; rg < 4; ++rg) {
#pragma unroll
      for (int ks = 0; ks < 2; ++ks) {
        const uint32_t b = lds[abase + rg * 896 + s * 8 + ks * 4];
        short8 af;
        UNPACK(af, b)
        acc[rg][0] = __builtin_amdgcn_mfma_f32_16x16x32_bf16(af, bf[ks][0], acc[rg][0], 0, 0, 0);
        acc[rg][1] = __builtin_amdgcn_mfma_f32_16x16x32_bf16(af, bf[ks][1], acc[rg][1], 0, 0, 0);
      }
    }
  }
#undef UNPACK

  const int jr = (lane >> 4) << 2;                 // C/D: row=(l>>4)*4+j, col=l&15
#pragma unroll
  for (int rg = 0; rg < 4; ++rg)
#pragma unroll
    for (int cg = 0; cg < 2; ++cg) {
      uint16_t* pt = part + (size_t)kc * (MD * HD)
                   + (size_t)(w * 64 + rg * 16 + jr) * HD + ch * 32 + cg * 16 + r16;
#pragma unroll
      for (int j = 0; j < 4; ++j)
        pt[j * HD] = f2bf(acc[rg][cg][j]);
    }
}

// ---------------------------------------------------------------------------
// Kernel 3 — identical to round 8 (verified).
// ---------------------------------------------------------------------------
__global__ __launch_bounds__(512) void k_reduce(const uint16_t* __restrict__ part,
                                                const float* __restrict__ cnt,
                                                float* __restrict__ pe) {
  __shared__ float red[512];
  const int r   = blockIdx.x;
  const int t   = threadIdx.x;
  const int col = t & 127;
  const int sub = t >> 7;
  const uint16_t* pp = part + (size_t)(sub * 28) * (MD * HD) + (size_t)r * HD + col;
  float s = 0.f;
#pragma unroll
  for (int i = 0; i < 28; ++i)
    s += __uint_as_float((uint32_t)pp[(size_t)i * (MD * HD)] << 16);
  red[t] = s;
  __syncthreads();
  if (t < 128) {
    const float tot = red[t] + red[t + 128] + red[t + 256] + red[t + 384];
    const float c   = cnt[r];
    pe[r * HD + t] = (c > 0.f) ? (tot / c) : 0.f;
  }
}

// ---------------------------------------------------------------------------
// Kernel 4 — identical to round 8 (verified).
// ---------------------------------------------------------------------------
__global__ __launch_bounds__(128) void k_tail(
    const float* __restrict__ pe,
    const float* __restrict__ w1, const float* __restrict__ b1,
    const float* __restrict__ w2, const float* __restrict__ b2,
    const float* __restrict__ ln1g, const float* __restrict__ ln1b,
    const float* __restrict__ ln2g, const float* __restrict__ ln2b,
    const float* __restrict__ bn1g, const float* __restrict__ bn1b,
    const float* __restrict__ bn2g, const float* __restrict__ bn2b,
    float* __restrict__ out) {
  const int b = blockIdx.x, t = threadIdx.x;
  __shared__ float sh[HD];
  __shared__ float red[HD];

  float x = 0.f;
#pragma unroll
  for (int p = 0; p < PD; ++p) x += pe[(b * PD + p) * HD + t];
  x *= (1.f / PD);

  const float bninv = rsqrtf(1.f + EPSF);

  // ---- LN1 ----
  red[t] = x; __syncthreads();
  for (int o = 64; o > 0; o >>= 1) { if (t < o) red[t] += red[t + o]; __syncthreads(); }
  const float mu1 = red[0] * (1.f / HD); __syncthreads();
  const float d1 = x - mu1;
  red[t] = d1 * d1; __syncthreads();
  for (int o = 64; o > 0; o >>= 1) { if (t < o) red[t] += red[t + o]; __syncthreads(); }
  const float v1 = red[0] * (1.f / HD); __syncthreads();
  const float y1 = ln1g[t] * d1 * rsqrtf(v1 + EPSF) + ln1b[t];

  // ---- FC1 + ReLU + BN1 ----
  sh[t] = y1; __syncthreads();
  float a = b1[t];
  const float4* wrow1 = (const float4*)(w1 + (size_t)t * HD);
#pragma unroll 8
  for (int k = 0; k < 32; ++k) {
    const float4 w = wrow1[k];
    a += w.x * sh[k * 4] + w.y * sh[k * 4 + 1] + w.z * sh[k * 4 + 2] + w.w * sh[k * 4 + 3];
  }
  a = fmaxf(a, 0.f);
  a = bn1g[t] * a * bninv + bn1b[t];
  __syncthreads();

  // ---- LN2 ----
  red[t] = a; __syncthreads();
  for (int o = 64; o > 0; o >>= 1) { if (t < o) red[t] += red[t + o]; __syncthreads(); }
  const float mu2 = red[0] * (1.f / HD); __syncthreads();
  const float d2 = a - mu2;
  red[t] = d2 * d2; __syncthreads();
  for (int o = 64; o > 0; o >>= 1) { if (t < o) red[t] += red[t + o]; __syncthreads(); }
  const float v2 = red[0] * (1.f / HD); __syncthreads();
  const float y2 = ln2g[t] * d2 * rsqrtf(v2 + EPSF) + ln2b[t];

  // ---- FC2 + ReLU + BN2 ----
  sh[t] = y2; __syncthreads();
  float a2 = b2[t];
  const float4* wrow2 = (const float4*)(w2 + (size_t)t * HD);
#pragma unroll 8
  for (int k = 0; k < 32; ++k) {
    const float4 w = wrow2[k];
    a2 += w.x * sh[k * 4] + w.y * sh[k * 4 + 1] + w.z * sh[k * 4 + 2] + w.w * sh[k * 4 + 3];
  }
  a2 = fmaxf(a2, 0.f);
  a2 = bn2g[t] * a2 * bninv + bn2b[t];
  out[b * HD + t] = a2;
}

// ---------------------------------------------------------------------------
// ATTRIBUTION EXPERIMENT 2: k_gemm launched TWICE (idempotent — part written
// identically both times). N = 62.0 + (gemm_warm + boundary).
// With r11 (prep+beta = 22.7): full per-kernel decomposition follows.
//   N ~ 68-73  -> gemm small -> reduce/boundaries are the hidden cost.
//   N ~ 85-95  -> gemm ~20-30 -> rebuild gemm (no-LDS free-run variant).
// ---------------------------------------------------------------------------
extern "C" void kernel_launch(void* const* d_in, const int* in_sizes, int n_in,
                              void* d_out, int out_size, void* d_ws, size_t ws_size,
                              hipStream_t stream) {
  const int*   inp  = (const int*)d_in[0];
  const float* emb  = (const float*)d_in[1];
  const float* w1   = (const float*)d_in[2];
  const float* b1   = (const float*)d_in[3];
  const float* w2   = (const float*)d_in[4];
  const float* b2   = (const float*)d_in[5];
  const float* ln1g = (const float*)d_in[6];
  const float* ln1b = (const float*)d_in[7];
  const float* ln2g = (const float*)d_in[8];
  const float* ln2b = (const float*)d_in[9];
  const float* bn1g = (const float*)d_in[10];
  const float* bn1b = (const float*)d_in[11];
  const float* bn2g = (const float*)d_in[12];
  const float* bn2b = (const float*)d_in[13];
  float* out = (float*)d_out;

  // workspace layout (31.0 MB total)
  char* ws = (char*)d_ws;
  uint8_t*  bitsT = (uint8_t*)ws;                          // 112*512*56 = 3,211,264 (+64 pad)
  uint16_t* embF  = (uint16_t*)(ws + 3211328);             // 784*16384  = 12,845,056
  uint16_t* part  = (uint16_t*)(ws + 3211328 + 12845056);  // 112*512*128*2 = 14,680,064
  float*    cnt   = (float*)(ws + 3211328 + 12845056 + 14680064);          // 2,048
  float*    pe    = (float*)(ws + 3211328 + 12845056 + 14680064 + 2048);   // 262,144

  k_prep<<<NEB + MD, 256, 0, stream>>>(emb, inp, embF, bitsT, cnt);
  k_gemm<<<NKC * 4, 512, 0, stream>>>(bitsT, embF, part);
  k_gemm<<<NKC * 4, 512, 0, stream>>>(bitsT, embF, part);   // duplicate (measurement)
  k_reduce<<<MD, 512, 0, stream>>>(part, cnt, pe);
  k_tail<<<BD, 128, 0, stream>>>(pe, w1, b1, w2, b2, ln1g, ln1b, ln2g, ln2b,
                                 bn1g, bn1b, bn2g, bn2b, out);
}

// Round 13
// 60.277 us; speedup vs baseline: 2.7992x; 1.3416x over previous
//
#include <hip/hip_runtime.h>
#include <stdint.h>

// Problem: B=32, P=16, E=50000, H=128
#define E_DIM 50000
#define EP2   50176          // padded: 196 * 256 = 784 * 64
#define HD    128
#define BD    32
#define PD    16
#define MD    512            // B*P
#define KCHUNK 256           // 4 stages of 64
#define NKC   196            // EP2 / KCHUNK exactly
#define NST   4
#define NEB   784            // embF 64-e units = EP2/64
#define EPSF  1e-5f

typedef short short8 __attribute__((ext_vector_type(8)));   // 8 bf16 (4 VGPRs)
typedef float f32x4  __attribute__((ext_vector_type(4)));

__device__ __forceinline__ uint16_t f2bf(float f) {
  uint32_t u = __float_as_uint(f);
  u += 0x7FFFu + ((u >> 16) & 1u);           // round-to-nearest-even
  return (uint16_t)(u >> 16);
}

// ---------------------------------------------------------------------------
// Kernel 1 (fused prep) — r8-verified; only the bitsT scatter formula changed
// to the 32 B/row-chunk layout: byte c0 -> bitsT[(c0>>5)*16384 + r*32 + (c0&31)].
// ---------------------------------------------------------------------------
__global__ __launch_bounds__(256) void k_prep(const float* __restrict__ emb,
                                              const int* __restrict__ inp,
                                              uint16_t* __restrict__ embF,
                                              uint8_t* __restrict__ bitsT,
                                              float* __restrict__ cnt) {
  __shared__ __align__(16) uint16_t lds[HD * 64];
  __shared__ int sc[4];
  const int t = threadIdx.x;

  if (blockIdx.x < NEB) {
    // ---- embF repack (r8-verified, unchanged) ----
    const int e0 = blockIdx.x * 64;
#pragma unroll
    for (int pass = 0; pass < 8; ++pass) {
      const int el = pass * 8 + (t >> 5);
      const int h  = (t & 31) * 4;
      const int eg = e0 + el;
      float4 v = {0.f, 0.f, 0.f, 0.f};
      if (eg < E_DIM && eg != 0)
        v = *(const float4*)(emb + (size_t)eg * HD + h);
      const uint16_t q0 = f2bf(v.x), q1 = f2bf(v.y), q2 = f2bf(v.z), q3 = f2bf(v.w);
      lds[(h + 0) * 64 + (el ^ (((h + 0) & 7) << 3))] = q0;
      lds[(h + 1) * 64 + (el ^ (((h + 1) & 7) << 3))] = q1;
      lds[(h + 2) * 64 + (el ^ (((h + 2) & 7) << 3))] = q2;
      lds[(h + 3) * 64 + (el ^ (((h + 3) & 7) << 3))] = q3;
    }
    __syncthreads();
    const int w    = t >> 6;
    const int lane = t & 63;
    const int r16  = lane & 15;
    const int kgq  = (lane >> 4) * 8;
    uint16_t* outp = embF + (size_t)blockIdx.x * 8192 + lane * 8;
#pragma unroll
    for (int fr = 0; fr < 4; ++fr) {
      const int f  = w * 4 + fr;               // 0..15: ks=f>>3, c4=f&7
      const int h  = (f & 7) * 16 + r16;
      const int el = (f >> 3) * 32 + kgq;
      short8 d = *(const short8*)(lds + h * 64 + (el ^ ((h & 7) << 3)));
      *(short8*)(outp + f * 512) = d;
    }
  } else {
    // ---- bit-pack one row into 32B/chunk kc-major bitsT ----
    const int r = blockIdx.x - NEB;
    const int* rp = inp + (size_t)r * E_DIM;
    int c = 0;
#pragma unroll 3
    for (int i = 0; i < 24; ++i) {
      const int idx = i * 2048 + t * 8;
      const int4 v0 = *(const int4*)(rp + idx);
      const int4 v1 = *(const int4*)(rp + idx + 4);
      const uint32_t b = (uint32_t)(v0.x == 1)        | ((uint32_t)(v0.y == 1) << 1)
                       | ((uint32_t)(v0.z == 1) << 2) | ((uint32_t)(v0.w == 1) << 3)
                       | ((uint32_t)(v1.x == 1) << 4) | ((uint32_t)(v1.y == 1) << 5)
                       | ((uint32_t)(v1.z == 1) << 6) | ((uint32_t)(v1.w == 1) << 7);
      c += __popc(b);
      const int c0 = i * 256 + t;
      bitsT[(size_t)(c0 >> 5) * 16384 + r * 32 + (c0 & 31)] = (uint8_t)b;
    }
    if (t < 106) {                             // bytes 6144..6249 real
      const int idx = 49152 + t * 8;
      const int4 v0 = *(const int4*)(rp + idx);
      const int4 v1 = *(const int4*)(rp + idx + 4);
      const uint32_t b = (uint32_t)(v0.x == 1)        | ((uint32_t)(v0.y == 1) << 1)
                       | ((uint32_t)(v0.z == 1) << 2) | ((uint32_t)(v0.w == 1) << 3)
                       | ((uint32_t)(v1.x == 1) << 4) | ((uint32_t)(v1.y == 1) << 5)
                       | ((uint32_t)(v1.z == 1) << 6) | ((uint32_t)(v1.w == 1) << 7);
      c += __popc(b);
      const int c0 = 6144 + t;
      bitsT[(size_t)(c0 >> 5) * 16384 + r * 32 + (c0 & 31)] = (uint8_t)b;
    } else if (t < 128) {                      // 6250..6271 zero pad
      const int c0 = 6144 + t;
      bitsT[(size_t)(c0 >> 5) * 16384 + r * 32 + (c0 & 31)] = 0;
    }
#pragma unroll
    for (int o = 1; o < 64; o <<= 1) c += __shfl_xor(c, o);
    if ((t & 63) == 0) sc[t >> 6] = c;
    __syncthreads();
    if (t == 0) cnt[r] = (float)(sc[0] + sc[1] + sc[2] + sc[3]);
  }
}

// ---------------------------------------------------------------------------
// Kernel 2: partial GEMM. Grid = 196 kc x 2 col-halves = 392 blocks x 512 thr.
// Per block: stage B half (32KB frag-packed) + A bits (16KB) in 48KB LDS,
// one barrier, 4 unrolled stages of pure LDS->MFMA. Each unpacked A-frag
// feeds 4 MFMAs (vs 2 in r8) -> VALU/MFMA balanced. A bytes read as u32
// broadcast (16 lanes same addr) + bfe -> cheap LDS traffic.
// ---------------------------------------------------------------------------
__global__ __launch_bounds__(512, 4) void k_gemm(const uint8_t* __restrict__ bitsT,
                                                 const uint16_t* __restrict__ embF,
                                                 uint16_t* __restrict__ part) {
  __shared__ __align__(16) uint8_t lds[49152];   // [0,32768): B frags, [32768,..): A bits

  const int t    = threadIdx.x;
  const int lane = t & 63;
  const int w    = t >> 6;
  const int kc   = blockIdx.x >> 1;
  const int ch   = blockIdx.x & 1;               // col half: cols ch*64..+63

  // ---- stage: B 2048x16B (dst linear), A 1024x16B ----
  {
    const char* eb = (const char*)embF;
    const char* ab = (const char*)bitsT + (size_t)kc * 16384;
#pragma unroll
    for (int i = 0; i < 4; ++i) {
      const int IDX = t + i * 512;               // [s:2][ks:1][cg:2][lane:6]
      const size_t src = (size_t)(kc * 4 + (IDX >> 9)) * 16384
                       + (size_t)((((IDX >> 8) & 1) * 8) + ch * 4 + ((IDX >> 6) & 3)) * 1024
                       + (size_t)(IDX & 63) * 16;
      *(uint4*)(lds + IDX * 16) = *(const uint4*)(eb + src);
    }
#pragma unroll
    for (int i = 0; i < 2; ++i) {
      const int IDX = t + i * 512;
      *(uint4*)(lds + 32768 + IDX * 16) = *(const uint4*)(ab + IDX * 16);
    }
  }
  __syncthreads();

  const int r16   = lane & 15;
  const int shamt = (lane >> 4) * 8;             // byte-select within u32
  const int abase = 32768 + (w * 64 + r16) * 32; // + rg*512 + s*8 + ks*4

  f32x4 acc[4][4];
#pragma unroll
  for (int rg = 0; rg < 4; ++rg)
#pragma unroll
    for (int cg = 0; cg < 4; ++cg) acc[rg][cg] = (f32x4){0.f, 0.f, 0.f, 0.f};

#define UNPACK(DST, B)                                            \
  {                                                               \
    union { uint32_t u[4]; short8 s; } x_;                        \
    x_.u[0] = ((B) & 1u) * 0x3F80u        + ((B) & 2u) * 0x1FC00000u;   \
    x_.u[1] = (((B) >> 2) & 1u) * 0x3F80u + (((B) >> 2) & 2u) * 0x1FC00000u; \
    x_.u[2] = (((B) >> 4) & 1u) * 0x3F80u + (((B) >> 4) & 2u) * 0x1FC00000u; \
    x_.u[3] = (((B) >> 6) & 1u) * 0x3F80u + (((B) >> 6) & 2u) * 0x1FC00000u; \
    DST = x_.s;                                                   \
  }

#pragma unroll
  for (int s = 0; s < NST; ++s) {
#pragma unroll
    for (int ks = 0; ks < 2; ++ks) {
      const uint8_t* bb = lds + s * 8192 + ks * 4096 + lane * 16;
      const short8 bf0 = *(const short8*)(bb);
      const short8 bf1 = *(const short8*)(bb + 1024);
      const short8 bf2 = *(const short8*)(bb + 2048);
      const short8 bf3 = *(const short8*)(bb + 3072);
#pragma unroll
      for (int rg = 0; rg < 4; ++rg) {
        const uint32_t b32 = *(const uint32_t*)(lds + abase + rg * 512 + s * 8 + ks * 4);
        const uint32_t b = (b32 >> shamt) & 0xFFu;
        short8 af;
        UNPACK(af, b)
        acc[rg][0] = __builtin_amdgcn_mfma_f32_16x16x32_bf16(af, bf0, acc[rg][0], 0, 0, 0);
        acc[rg][1] = __builtin_amdgcn_mfma_f32_16x16x32_bf16(af, bf1, acc[rg][1], 0, 0, 0);
        acc[rg][2] = __builtin_amdgcn_mfma_f32_16x16x32_bf16(af, bf2, acc[rg][2], 0, 0, 0);
        acc[rg][3] = __builtin_amdgcn_mfma_f32_16x16x32_bf16(af, bf3, acc[rg][3], 0, 0, 0);
      }
    }
  }
#undef UNPACK

  // ---- epilogue: bf16 partial tile [kc][row][col] ----
  const int jr = (lane >> 4) << 2;               // C/D: row=(l>>4)*4+j, col=l&15
#pragma unroll
  for (int rg = 0; rg < 4; ++rg)
#pragma unroll
    for (int cg = 0; cg < 4; ++cg) {
      uint16_t* pt = part + (size_t)kc * (MD * HD)
                   + (size_t)(w * 64 + rg * 16 + jr) * HD + ch * 64 + cg * 16 + r16;
#pragma unroll
      for (int j = 0; j < 4; ++j)
        pt[j * HD] = f2bf(acc[rg][cg][j]);
    }
}

// ---------------------------------------------------------------------------
// Kernel 3: reduce bf16 partials over 196 kc -> path_emb [512][128].
// Vectorized: short8 per load (1KB/wave-instr), 16-way kc split + LDS combine.
// ---------------------------------------------------------------------------
__global__ __launch_bounds__(256) void k_reduce(const uint16_t* __restrict__ part,
                                                const float* __restrict__ cnt,
                                                float* __restrict__ pe) {
  __shared__ float red[16 * 128];
  const int r    = blockIdx.x;
  const int t    = threadIdx.x;
  const int col8 = t & 15;
  const int sub  = t >> 4;                       // 0..15
  float s0=0.f,s1=0.f,s2=0.f,s3=0.f,s4=0.f,s5=0.f,s6=0.f,s7=0.f;
  const uint16_t* pp = part + (size_t)r * HD + col8 * 8;
  for (int kc = sub; kc < NKC; kc += 16) {
    const short8 v = *(const short8*)(pp + (size_t)kc * (MD * HD));
    s0 += __uint_as_float((uint32_t)(uint16_t)v[0] << 16);
    s1 += __uint_as_float((uint32_t)(uint16_t)v[1] << 16);
    s2 += __uint_as_float((uint32_t)(uint16_t)v[2] << 16);
    s3 += __uint_as_float((uint32_t)(uint16_t)v[3] << 16);
    s4 += __uint_as_float((uint32_t)(uint16_t)v[4] << 16);
    s5 += __uint_as_float((uint32_t)(uint16_t)v[5] << 16);
    s6 += __uint_as_float((uint32_t)(uint16_t)v[6] << 16);
    s7 += __uint_as_float((uint32_t)(uint16_t)v[7] << 16);
  }
  float* rd = red + sub * 128 + col8 * 8;
  rd[0]=s0; rd[1]=s1; rd[2]=s2; rd[3]=s3; rd[4]=s4; rd[5]=s5; rd[6]=s6; rd[7]=s7;
  __syncthreads();
  if (t < 128) {
    float tot = 0.f;
#pragma unroll
    for (int k = 0; k < 16; ++k) tot += red[k * 128 + t];
    const float c = cnt[r];
    pe[r * HD + t] = (c > 0.f) ? (tot / c) : 0.f;
  }
}

// ---------------------------------------------------------------------------
// Kernel 4 — identical to round 8 (verified).
// ---------------------------------------------------------------------------
__global__ __launch_bounds__(128) void k_tail(
    const float* __restrict__ pe,
    const float* __restrict__ w1, const float* __restrict__ b1,
    const float* __restrict__ w2, const float* __restrict__ b2,
    const float* __restrict__ ln1g, const float* __restrict__ ln1b,
    const float* __restrict__ ln2g, const float* __restrict__ ln2b,
    const float* __restrict__ bn1g, const float* __restrict__ bn1b,
    const float* __restrict__ bn2g, const float* __restrict__ bn2b,
    float* __restrict__ out) {
  const int b = blockIdx.x, t = threadIdx.x;
  __shared__ float sh[HD];
  __shared__ float red[HD];

  float x = 0.f;
#pragma unroll
  for (int p = 0; p < PD; ++p) x += pe[(b * PD + p) * HD + t];
  x *= (1.f / PD);

  const float bninv = rsqrtf(1.f + EPSF);

  // ---- LN1 ----
  red[t] = x; __syncthreads();
  for (int o = 64; o > 0; o >>= 1) { if (t < o) red[t] += red[t + o]; __syncthreads(); }
  const float mu1 = red[0] * (1.f / HD); __syncthreads();
  const float d1 = x - mu1;
  red[t] = d1 * d1; __syncthreads();
  for (int o = 64; o > 0; o >>= 1) { if (t < o) red[t] += red[t + o]; __syncthreads(); }
  const float v1 = red[0] * (1.f / HD); __syncthreads();
  const float y1 = ln1g[t] * d1 * rsqrtf(v1 + EPSF) + ln1b[t];

  // ---- FC1 + ReLU + BN1 ----
  sh[t] = y1; __syncthreads();
  float a = b1[t];
  const float4* wrow1 = (const float4*)(w1 + (size_t)t * HD);
#pragma unroll 8
  for (int k = 0; k < 32; ++k) {
    const float4 w = wrow1[k];
    a += w.x * sh[k * 4] + w.y * sh[k * 4 + 1] + w.z * sh[k * 4 + 2] + w.w * sh[k * 4 + 3];
  }
  a = fmaxf(a, 0.f);
  a = bn1g[t] * a * bninv + bn1b[t];
  __syncthreads();

  // ---- LN2 ----
  red[t] = a; __syncthreads();
  for (int o = 64; o > 0; o >>= 1) { if (t < o) red[t] += red[t + o]; __syncthreads(); }
  const float mu2 = red[0] * (1.f / HD); __syncthreads();
  const float d2 = a - mu2;
  red[t] = d2 * d2; __syncthreads();
  for (int o = 64; o > 0; o >>= 1) { if (t < o) red[t] += red[t + o]; __syncthreads(); }
  const float v2 = red[0] * (1.f / HD); __syncthreads();
  const float y2 = ln2g[t] * d2 * rsqrtf(v2 + EPSF) + ln2b[t];

  // ---- FC2 + ReLU + BN2 ----
  sh[t] = y2; __syncthreads();
  float a2 = b2[t];
  const float4* wrow2 = (const float4*)(w2 + (size_t)t * HD);
#pragma unroll 8
  for (int k = 0; k < 32; ++k) {
    const float4 w = wrow2[k];
    a2 += w.x * sh[k * 4] + w.y * sh[k * 4 + 1] + w.z * sh[k * 4 + 2] + w.w * sh[k * 4 + 3];
  }
  a2 = fmaxf(a2, 0.f);
  a2 = bn2g[t] * a2 * bninv + bn2b[t];
  out[b * HD + t] = a2;
}

// ---------------------------------------------------------------------------
extern "C" void kernel_launch(void* const* d_in, const int* in_sizes, int n_in,
                              void* d_out, int out_size, void* d_ws, size_t ws_size,
                              hipStream_t stream) {
  const int*   inp  = (const int*)d_in[0];
  const float* emb  = (const float*)d_in[1];
  const float* w1   = (const float*)d_in[2];
  const float* b1   = (const float*)d_in[3];
  const float* w2   = (const float*)d_in[4];
  const float* b2   = (const float*)d_in[5];
  const float* ln1g = (const float*)d_in[6];
  const float* ln1b = (const float*)d_in[7];
  const float* ln2g = (const float*)d_in[8];
  const float* ln2b = (const float*)d_in[9];
  const float* bn1g = (const float*)d_in[10];
  const float* bn1b = (const float*)d_in[11];
  const float* bn2g = (const float*)d_in[12];
  const float* bn2b = (const float*)d_in[13];
  float* out = (float*)d_out;

  // workspace layout (~42 MB of ~400 MB ws)
  char* ws = (char*)d_ws;
  uint8_t*  bitsT = (uint8_t*)ws;                          // 196*16384 = 3,211,264 (+64 pad)
  uint16_t* embF  = (uint16_t*)(ws + 3211328);             // 784*16384 = 12,845,056
  uint16_t* part  = (uint16_t*)(ws + 3211328 + 12845056);  // 196*512*128*2 = 25,690,112
  float*    cnt   = (float*)(ws + 3211328 + 12845056 + 25690112);          // 2,048
  float*    pe    = (float*)(ws + 3211328 + 12845056 + 25690112 + 2048);   // 262,144

  k_prep<<<NEB + MD, 256, 0, stream>>>(emb, inp, embF, bitsT, cnt);
  k_gemm<<<NKC * 2, 512, 0, stream>>>(bitsT, embF, part);
  k_reduce<<<MD, 256, 0, stream>>>(part, cnt, pe);
  k_tail<<<BD, 128, 0, stream>>>(pe, w1, b1, w2, b2, ln1g, ln1b, ln2g, ln2b,
                                 bn1g, bn1b, bn2g, bn2b, out);
}